// Round 10
// baseline (333.962 us; speedup 1.0000x reference)
//
#include <hip/hip_runtime.h>
#include <hip/hip_bf16.h>
#include <cstdint>
#include <cstddef>

typedef __attribute__((ext_vector_type(8))) short bf16x8;
typedef __attribute__((ext_vector_type(4))) float f32x4;

#define PI2F 6.283185307179586f

__device__ __forceinline__ float bf2f(unsigned short u) {
  union { float f; uint32_t i; } x; x.i = ((uint32_t)u) << 16; return x.f;
}
__device__ __forceinline__ unsigned short f2bf(float f) {
  union { float f; uint32_t i; } x; x.f = f;
  uint32_t r = x.i + 0x7FFF + ((x.i >> 16) & 1);
  return (unsigned short)(r >> 16);
}

// async global->LDS, 16B per lane, dest = wave-uniform base + lane*16
__device__ __forceinline__ void glds16(const void* g, void* l) {
  __builtin_amdgcn_global_load_lds(
      (const __attribute__((address_space(1))) unsigned int*)g,
      (__attribute__((address_space(3))) unsigned int*)l, 16, 0, 0);
}

// ---------------- zero-init: 256B zero page + 256B x0 tail pad ----------------
__global__ void zinit_kernel(unsigned short* __restrict__ zp, unsigned short* __restrict__ pad) {
  int t = threadIdx.x;   // 128 threads
  zp[t] = 0;
  pad[t] = 0;
}

// ---------------- per-row 128-pt DFT ----------------
__global__ void dft_kernel(const float* __restrict__ img, float2* __restrict__ col,
                           float2* __restrict__ tw) {
  __shared__ float row[128];
  __shared__ float2 twl[128];
  const int bh = blockIdx.x;      // b*128 + h
  const int i = threadIdx.x;      // 0..127
  row[i] = img[bh * 128 + i];
  float s, c;
  sincosf(PI2F * (float)i / 128.0f, &s, &c);
  twl[i] = make_float2(c, s);
  __syncthreads();
  if (bh == 0) tw[i] = twl[i];
  float sr = 0.f, si = 0.f;
  for (int w = 0; w < 128; ++w) {
    float v = row[w];
    float2 t = twl[(i * w) & 127];
    sr += v * t.x;
    si -= v * t.y;
  }
  col[bh * 128 + i] = make_float2(sr * (1.0f / 128.0f), si * (1.0f / 128.0f));
}

// ---------------- spectral sep + mask -> x0 channels-last [8][128][128][144] bf16
__global__ __launch_bounds__(256)
void sep_cl_kernel(const float2* __restrict__ col, const float2* __restrict__ tw,
                   const float* __restrict__ maskE, unsigned short* __restrict__ x0) {
  __shared__ unsigned short lt[128][132];   // [c][w], +4 pad
  __shared__ float2 twl[128];
  const int bh = blockIdx.x;
  const int b = bh >> 7, h = bh & 127;
  const int tid = threadIdx.x;
  if (tid < 128) twl[tid] = tw[tid];
  __syncthreads();
  {
    const int c = tid >> 1;
    const int w0 = (tid & 1) * 64;
    float2 cv = col[(b * 128 + h) * 128 + c];
#pragma unroll 8
    for (int j = 0; j < 64; ++j) {
      int w = w0 + j;
      float2 t = twl[(w * c) & 127];
      lt[c][w] = f2bf(cv.x * t.x - cv.y * t.y);
    }
  }
  __syncthreads();
  if (tid < 144) {
    const int c = tid;
    unsigned short* dst = x0 + ((size_t)bh * 128) * 144 + c;
    if (c < 128) {
      for (int w = 0; w < 128; ++w) dst[(size_t)w * 144] = lt[c][w];
    } else if (c < 134) {
      const float* m = maskE + ((size_t)(b * 6 + (c - 128)) * 128 + h) * 128;
      for (int w = 0; w < 128; ++w) dst[(size_t)w * 144] = f2bf(m[w]);
    } else {
      for (int w = 0; w < 128; ++w) dst[(size_t)w * 144] = 0;
    }
  }
}

// ---------------- weight convert + permute: src[m][ci][t] fp32 -> dst[m][t*CINP+ci] bf16
template<int CIN, int CINP>
__global__ __launch_bounds__(256)
void cvtperm_kernel(const float* __restrict__ src, unsigned short* __restrict__ dst) {
  __shared__ unsigned short tile[16][68];
  const int m = blockIdx.y;
  const int ci0 = blockIdx.x * 64;
  const int tid = threadIdx.x;
  {
    const int ci = ci0 + (tid >> 2);
    const int t0 = (tid & 3) * 4;
    float4 v = make_float4(0.f, 0.f, 0.f, 0.f);
    if (ci < CIN) v = *reinterpret_cast<const float4*>(&src[((size_t)m * CIN + ci) * 16 + t0]);
    const int cr = tid >> 2;
    tile[t0 + 0][cr] = f2bf(v.x);
    tile[t0 + 1][cr] = f2bf(v.y);
    tile[t0 + 2][cr] = f2bf(v.z);
    tile[t0 + 3][cr] = f2bf(v.w);
  }
  __syncthreads();
  {
    const int t = tid >> 4;
    const int co = (tid & 15) * 4;
    const int ci = ci0 + co;
    if (ci < CINP) {
      ushort4 o;
      o.x = tile[t][co]; o.y = tile[t][co + 1]; o.z = tile[t][co + 2]; o.w = tile[t][co + 3];
      *reinterpret_cast<ushort4*>(&dst[(size_t)m * (16 * CINP) + (size_t)t * CINP + ci]) = o;
    }
  }
}

// ---------------- channels-last conv, 128x128 tile, global_load_lds staging ----------
// k = tap*CINP + ci. Split-K over whole taps (TPS = 16/NSPLIT).
// 256 thr = 4 waves (2x2), wave tile 64x64 (4x4 frags). One barrier per 32-k-step.
// LDS image swizzled via pre-swizzled per-lane GLOBAL addresses (dest stays linear).
template<int CINP, int CSTOR, int COUT, int HI, int WI, int HO, int WO, int NSPLIT, bool FUSED>
__global__ __launch_bounds__(256, 2)
void conv_cl4_kernel(const unsigned short* __restrict__ X,
                     const unsigned short* __restrict__ Wt,
                     const unsigned short* __restrict__ zp,
                     const float* __restrict__ bias,
                     unsigned short* __restrict__ Y,
                     float* __restrict__ P) {
  constexpr int KTOT = 16 * CINP;
  constexpr int CPT = CINP / 32;          // k-chunks per tap
  constexpr int HOWO = HO * WO;
  constexpr int LHW = __builtin_ctz(HOWO);
  constexpr int LWO = __builtin_ctz(WO);
  constexpr int TPS = 16 / NSPLIT;        // taps per split
  constexpr size_t PSTRIDE = (size_t)8 * HOWO * COUT;
  constexpr int NIT = TPS * CPT;

  __shared__ __align__(16) unsigned short As[2][4096];   // [row 0..127][4 slots x 8 shorts]
  __shared__ __align__(16) unsigned short Bs[2][4096];

  const int tid = threadIdx.x;
  const int lane = tid & 63;
  const int wv = tid >> 6;
  const int wm = wv >> 1, wn = wv & 1;
  const int n0 = blockIdx.x * 128;
  const int m0 = blockIdx.y * 128;
  const int split = blockIdx.z;
  const int r = lane & 15, g = lane >> 4;

  // staging geometry: thread -> rows row0, row0+64; linear LDS slot = chk.
  // inverse-swizzle the SOURCE chunk so slot chk holds data chunk (chk-(row>>1))&3.
  const int row0 = tid >> 2;
  const int row1 = row0 + 64;
  const int chk = tid & 3;
  const int kofs = (((chk - ((row0 >> 1) & 3)) & 3)) * 8;   // same for row1 (row1=row0+64)

  int bb0, bho0, bwo0, bb1, bho1, bwo1;
  {
    int rn0 = n0 + row0, rn1 = n0 + row1;
    bb0 = rn0 >> LHW; bb1 = rn1 >> LHW;
    int re0 = rn0 & (HOWO - 1), re1 = rn1 & (HOWO - 1);
    bho0 = re0 >> LWO; bho1 = re1 >> LWO;
    bwo0 = re0 & (WO - 1); bwo1 = re1 & (WO - 1);
  }

  const int tap0 = split * TPS;
  int tapI = tap0, ccI = 0;              // issue pointer
  size_t boff0, boff1; bool bok0, bok1;
  auto tap_geom = [&](int t) {
    int kh = t >> 2, kw = t & 3;
    {
      int h = 2 * bho0 - 1 + kh, w = 2 * bwo0 - 1 + kw;
      bool hv = (unsigned)h < (unsigned)HI, wvv = (unsigned)w < (unsigned)WI;
      bok0 = hv && wvv;
      boff0 = (((size_t)bb0 * HI + (hv ? h : 0)) * WI + (wvv ? w : 0)) * (size_t)CSTOR;
    }
    {
      int h = 2 * bho1 - 1 + kh, w = 2 * bwo1 - 1 + kw;
      bool hv = (unsigned)h < (unsigned)HI, wvv = (unsigned)w < (unsigned)WI;
      bok1 = hv && wvv;
      boff1 = (((size_t)bb1 * HI + (hv ? h : 0)) * WI + (wvv ? w : 0)) * (size_t)CSTOR;
    }
  };
  tap_geom(tapI);

  auto issue = [&](int buf) {
    const int kk = tapI * CINP + ccI * 32 + kofs;
    glds16(Wt + (size_t)(m0 + row0) * KTOT + kk, &As[buf][wv * 512]);
    glds16(Wt + (size_t)(m0 + row1) * KTOT + kk, &As[buf][2048 + wv * 512]);
    const int ci = ccI * 32 + kofs;
    glds16(bok0 ? (X + boff0 + ci) : zp, &Bs[buf][wv * 512]);
    glds16(bok1 ? (X + boff1 + ci) : zp, &Bs[buf][2048 + wv * 512]);
  };
  auto advance = [&]() {
    ccI++;
    if (ccI == CPT) { ccI = 0; tapI++; if (tapI < tap0 + TPS) tap_geom(tapI); }
  };

  f32x4 acc[4][4] = {};

  issue(0); advance();
  for (int it = 0; it < NIT; ++it) {
    __syncthreads();                 // vmcnt(0) drain: phase-it loads landed; prior reads done
    if (it + 1 < NIT) { issue((it + 1) & 1); advance(); }
    const int buf = it & 1;
    bf16x8 af[4], bf[4];
#pragma unroll
    for (int mi = 0; mi < 4; ++mi) {
      int rw = wm * 64 + mi * 16 + r;
      af[mi] = *reinterpret_cast<const bf16x8*>(
          &As[buf][rw * 32 + (((g + ((rw >> 1) & 3)) & 3) * 8)]);
    }
#pragma unroll
    for (int ni = 0; ni < 4; ++ni) {
      int rw = wn * 64 + ni * 16 + r;
      bf[ni] = *reinterpret_cast<const bf16x8*>(
          &Bs[buf][rw * 32 + (((g + ((rw >> 1) & 3)) & 3) * 8)]);
    }
#pragma unroll
    for (int mi = 0; mi < 4; ++mi)
#pragma unroll
      for (int ni = 0; ni < 4; ++ni)
        acc[mi][ni] = __builtin_amdgcn_mfma_f32_16x16x32_bf16(af[mi], bf[ni], acc[mi][ni], 0, 0, 0);
  }

  // epilogue: C frag mapping col(n)=lane&15=r, row(m)=g*4+q
#pragma unroll
  for (int ni = 0; ni < 4; ++ni) {
    int n = n0 + wn * 64 + ni * 16 + r;
    int b = n >> LHW;
    int rem = n & (HOWO - 1);
    size_t obase = ((size_t)b * HOWO + rem) * COUT;
#pragma unroll
    for (int mi = 0; mi < 4; ++mi) {
      int mb = m0 + wm * 64 + mi * 16 + g * 4;
      f32x4 a = acc[mi][ni];
      if constexpr (FUSED) {
        float v0 = a[0] + bias[mb + 0]; v0 = v0 > 0.f ? v0 : 0.2f * v0;
        float v1 = a[1] + bias[mb + 1]; v1 = v1 > 0.f ? v1 : 0.2f * v1;
        float v2 = a[2] + bias[mb + 2]; v2 = v2 > 0.f ? v2 : 0.2f * v2;
        float v3 = a[3] + bias[mb + 3]; v3 = v3 > 0.f ? v3 : 0.2f * v3;
        ushort4 o;
        o.x = f2bf(v0); o.y = f2bf(v1); o.z = f2bf(v2); o.w = f2bf(v3);
        *reinterpret_cast<ushort4*>(&Y[obase + mb]) = o;
      } else {
        *reinterpret_cast<float4*>(&P[split * PSTRIDE + obase + mb]) =
            make_float4(a[0], a[1], a[2], a[3]);
      }
    }
  }
}

// ---------------- NHWC split-reduce + instance norm + lrelu -> bf16 (single read) ----
template<int HOWO, int COUT, int NSPLIT>
__global__ __launch_bounds__(256)
void inorm_cl3_kernel(const float* __restrict__ P, unsigned short* __restrict__ Y) {
  constexpr int PER = HOWO / 32;
  constexpr size_t PSTRIDE = (size_t)8 * HOWO * COUT;
  const int b = blockIdx.y;
  const int cl = threadIdx.x & 7;
  const int c = blockIdx.x * 8 + cl;
  const int hw0 = threadIdx.x >> 3;   // 0..31
  const float* base = P + ((size_t)b * HOWO) * COUT + c;
  float v[PER];
  float s1 = 0.f, s2 = 0.f;
#pragma unroll
  for (int j = 0; j < PER; ++j) {
    int hw = hw0 + j * 32;
    float x = 0.f;
#pragma unroll
    for (int s = 0; s < NSPLIT; ++s) x += base[s * PSTRIDE + (size_t)hw * COUT];
    v[j] = x; s1 += x; s2 += x * x;
  }
  __shared__ float r1[32][9], r2[32][9];
  __shared__ float ms[8], rs[8];
  r1[hw0][cl] = s1; r2[hw0][cl] = s2;
  __syncthreads();
  if (threadIdx.x < 8) {
    float a1 = 0.f, a2 = 0.f;
#pragma unroll
    for (int i = 0; i < 32; ++i) { a1 += r1[i][threadIdx.x]; a2 += r2[i][threadIdx.x]; }
    float mean = a1 * (1.0f / HOWO);
    float var = a2 * (1.0f / HOWO) - mean * mean;
    ms[threadIdx.x] = mean;
    rs[threadIdx.x] = rsqrtf(var + 1e-5f);
  }
  __syncthreads();
  const float mean = ms[cl], rstd = rs[cl];
  unsigned short* yb = Y + ((size_t)b * HOWO) * COUT + c;
#pragma unroll
  for (int j = 0; j < PER; ++j) {
    int hw = hw0 + j * 32;
    float t = (v[j] - mean) * rstd;
    t = t > 0.f ? t : 0.2f * t;
    yb[(size_t)hw * COUT] = f2bf(t);
  }
}

// ---------------- NHWC avg pool 8x8: [8][64][1024] -> pooled [8][1024] fp32 --------
__global__ __launch_bounds__(256)
void pool_cl_kernel(const unsigned short* __restrict__ X, float* __restrict__ pooled) {
  const int b = blockIdx.x;
  const int c4 = threadIdx.x * 4;
  float4 acc = make_float4(0.f, 0.f, 0.f, 0.f);
  for (int hw = 0; hw < 64; ++hw) {
    ushort4 v = *reinterpret_cast<const ushort4*>(&X[((size_t)b * 64 + hw) * 1024 + c4]);
    acc.x += bf2f(v.x); acc.y += bf2f(v.y); acc.z += bf2f(v.z); acc.w += bf2f(v.w);
  }
  acc.x *= (1.0f / 64.0f); acc.y *= (1.0f / 64.0f);
  acc.z *= (1.0f / 64.0f); acc.w *= (1.0f / 64.0f);
  *reinterpret_cast<float4*>(&pooled[b * 1024 + c4]) = acc;
}

// ---------------- final linear ----------------
__global__ __launch_bounds__(64)
void fc_kernel(const float* __restrict__ pooled, const float* __restrict__ w4,
               const float* __restrict__ b4, float* __restrict__ out) {
  const int bo = blockIdx.x;
  const int b = bo >> 7, o = bo & 127;
  const int lane = threadIdx.x;
  float s = 0.f;
#pragma unroll
  for (int j = 0; j < 16; ++j) {
    int c = lane + j * 64;
    s += pooled[b * 1024 + c] * w4[o * 1024 + c];
  }
#pragma unroll
  for (int off = 32; off > 0; off >>= 1) s += __shfl_xor(s, off);
  if (lane == 0) out[bo] = s + b4[o];
}

extern "C" void kernel_launch(void* const* d_in, const int* in_sizes, int n_in,
                              void* d_out, int out_size, void* d_ws, size_t ws_size,
                              hipStream_t stream) {
  (void)in_sizes; (void)n_in; (void)out_size; (void)ws_size;
  const float* image = (const float*)d_in[0];
  const float* maskE = (const float*)d_in[1];
  const float* w0 = (const float*)d_in[2];
  const float* b0 = (const float*)d_in[3];
  const float* w1 = (const float*)d_in[4];
  const float* w2 = (const float*)d_in[6];
  const float* w3 = (const float*)d_in[8];
  const float* w4 = (const float*)d_in[10];
  const float* b4 = (const float*)d_in[11];
  float* out = (float*)d_out;

  char* ws = (char*)d_ws;
  size_t off = 0;
  auto alloc = [&](size_t bytes) -> void* {
    void* p = ws + off;
    off = (off + bytes + 255) & ~(size_t)255;
    return p;
  };

  const size_t X0BYTES = (size_t)8 * 128 * 128 * 144 * 2;   // 37,748,736
  // wbuf: one 32MB permuted-weight buffer, stream-ordered reuse.
  unsigned short* wbuf = (unsigned short*)alloc((size_t)1024 * 16384 * 2);
  // bufA: x0cl (+256B zeroed tail pad), later fp32 split partials (<=33.6MB).
  char* bufA = (char*)alloc(X0BYTES + 256);
  // bufB: NHWC activations a0 (16.8MB) / a1 / a2 / a3, sequential reuse.
  char* bufB = (char*)alloc((size_t)8 * 4096 * 256 * 2);
  float2* col = (float2*)alloc((size_t)131072 * sizeof(float2));
  float2* tw = (float2*)alloc(128 * sizeof(float2));
  float* pooled = (float*)alloc(8192 * 4);
  unsigned short* zp = (unsigned short*)alloc(256);          // 256B zero page

  unsigned short* x0 = (unsigned short*)bufA;
  unsigned short* x0pad = (unsigned short*)(bufA + X0BYTES);
  float* part = (float*)bufA;
  unsigned short* a0 = (unsigned short*)bufB;
  unsigned short* a1 = (unsigned short*)bufB;
  unsigned short* a2 = (unsigned short*)bufB;
  unsigned short* a3 = (unsigned short*)bufB;

  // zero page + x0 tail pad
  zinit_kernel<<<1, 128, 0, stream>>>(zp, x0pad);

  // spectral map (channels-last)
  dft_kernel<<<1024, 128, 0, stream>>>(image, col, tw);
  sep_cl_kernel<<<1024, 256, 0, stream>>>(col, tw, maskE, x0);

  // conv0: 134(pad160)->256, fused bias+lrelu, full K
  cvtperm_kernel<134, 160><<<dim3(3, 256), 256, 0, stream>>>(w0, wbuf);
  conv_cl4_kernel<160, 144, 256, 128, 128, 64, 64, 1, true>
      <<<dim3(256, 2, 1), 256, 0, stream>>>(x0, wbuf, zp, b0, a0, nullptr);

  // conv1: 256->512, split-K 2 (8 taps each)
  cvtperm_kernel<256, 256><<<dim3(4, 512), 256, 0, stream>>>(w1, wbuf);
  conv_cl4_kernel<256, 256, 512, 64, 64, 32, 32, 2, false>
      <<<dim3(64, 4, 2), 256, 0, stream>>>(a0, wbuf, zp, nullptr, nullptr, part);
  inorm_cl3_kernel<1024, 512, 2><<<dim3(64, 8), 256, 0, stream>>>(part, a1);

  // conv2: 512->1024, split-K 4 (4 taps each)
  cvtperm_kernel<512, 512><<<dim3(8, 1024), 256, 0, stream>>>(w2, wbuf);
  conv_cl4_kernel<512, 512, 1024, 32, 32, 16, 16, 4, false>
      <<<dim3(16, 8, 4), 256, 0, stream>>>(a1, wbuf, zp, nullptr, nullptr, part);
  inorm_cl3_kernel<256, 1024, 4><<<dim3(128, 8), 256, 0, stream>>>(part, a2);

  // conv3: 1024->1024, split-K 16 (1 tap each)
  cvtperm_kernel<1024, 1024><<<dim3(16, 1024), 256, 0, stream>>>(w3, wbuf);
  conv_cl4_kernel<1024, 1024, 1024, 16, 16, 8, 8, 16, false>
      <<<dim3(4, 8, 16), 256, 0, stream>>>(a2, wbuf, zp, nullptr, nullptr, part);
  inorm_cl3_kernel<64, 1024, 16><<<dim3(128, 8), 256, 0, stream>>>(part, a3);

  // pool + fc
  pool_cl_kernel<<<8, 256, 0, stream>>>(a3, pooled);
  fc_kernel<<<1024, 64, 0, stream>>>(pooled, w4, b4, out);
}